// Round 1
// baseline (125.373 us; speedup 1.0000x reference)
//
#include <hip/hip_runtime.h>

#define FEAT_D 4096
#define MARGIN_F 0.5f
#define EPS_F 1e-6f

__global__ __launch_bounds__(256) void triplet_loss_kernel(
    const float* __restrict__ features,
    const float* __restrict__ label,
    const int* __restrict__ idx1,
    const int* __restrict__ idx2,
    float* __restrict__ out)
{
    const int row = blockIdx.x;
    const int tid = threadIdx.x;
    const int i1 = idx1[row];
    const int i2 = idx2[row];

    const float* a  = features + (size_t)row * FEAT_D;
    const float* t1 = features + (size_t)i1  * FEAT_D;
    const float* t2 = features + (size_t)i2  * FEAT_D;

    float s1 = 0.f, s2 = 0.f;

    // 4096 floats / 256 threads = 16 per thread = 4 x float4, coalesced:
    // chunk k covers floats [k*1024, k*1024+1024); thread t takes [t*4, t*4+4).
#pragma unroll
    for (int k = 0; k < 4; ++k) {
        const int base = k * 1024 + tid * 4;
        const float4 va = *reinterpret_cast<const float4*>(a  + base);
        const float4 v1 = *reinterpret_cast<const float4*>(t1 + base);
        const float4 v2 = *reinterpret_cast<const float4*>(t2 + base);
        float d;
        d = va.x - v1.x + EPS_F; s1 += d * d;
        d = va.y - v1.y + EPS_F; s1 += d * d;
        d = va.z - v1.z + EPS_F; s1 += d * d;
        d = va.w - v1.w + EPS_F; s1 += d * d;
        d = va.x - v2.x + EPS_F; s2 += d * d;
        d = va.y - v2.y + EPS_F; s2 += d * d;
        d = va.z - v2.z + EPS_F; s2 += d * d;
        d = va.w - v2.w + EPS_F; s2 += d * d;
    }

    // wave64 shuffle reduce
#pragma unroll
    for (int off = 32; off > 0; off >>= 1) {
        s1 += __shfl_down(s1, off, 64);
        s2 += __shfl_down(s2, off, 64);
    }

    __shared__ float sh1[4], sh2[4];
    const int wave = tid >> 6;
    const int lane = tid & 63;
    if (lane == 0) { sh1[wave] = s1; sh2[wave] = s2; }
    __syncthreads();

    if (tid == 0) {
        const float S1 = sh1[0] + sh1[1] + sh1[2] + sh1[3];
        const float S2 = sh2[0] + sh2[1] + sh2[2] + sh2[3];
        const float lab = label[row];
        const float d1 = fabsf(lab - label[i1]);
        const float d2 = fabsf(lab - label[i2]);
        const bool swap = (d1 >= d2);
        const float sn = swap ? S2 : S1;
        const float sf = swap ? S1 : S2;
        const float loss = fmaxf(sqrtf(sn) - sqrtf(sf) + MARGIN_F, 0.f);
        atomicAdd(out, loss);
    }
}

extern "C" void kernel_launch(void* const* d_in, const int* in_sizes, int n_in,
                              void* d_out, int out_size, void* d_ws, size_t ws_size,
                              hipStream_t stream) {
    const float* features = (const float*)d_in[0];
    const float* label    = (const float*)d_in[1];
    const int*   idx1     = (const int*)d_in[2];
    const int*   idx2     = (const int*)d_in[3];
    float* out = (float*)d_out;

    const int B = in_sizes[1];  // label has B elements ([B,1])

    hipMemsetAsync(out, 0, sizeof(float), stream);
    triplet_loss_kernel<<<B, 256, 0, stream>>>(features, label, idx1, idx2, out);
}